// Round 21
// baseline (151.264 us; speedup 1.0000x reference)
//
#include <hip/hip_runtime.h>
#include <hip/hip_bf16.h>

#define D_MODEL 1024
#define NHEADS  16
#define DH      64
#define SEQ     2048
#define BATCH   2

#define LOG2E 1.4426950408889634f
#define MASKB2 (-1e-6f * LOG2E)   // mask value in exp2 domain
#define DEFER_THR 11.5456f        // 8 * log2e
#define NEG_INF (-__builtin_inff())

typedef __attribute__((ext_vector_type(8))) short short8;
typedef __attribute__((ext_vector_type(4))) short short4v;
typedef __attribute__((ext_vector_type(4))) float f32x4;

#define AS1C(p) ((const __attribute__((address_space(1))) void*)(p))
#define AS3(p)  ((__attribute__((address_space(3))) void*)(p))

union PB { short4v s4; unsigned int u[2]; };
union VU { short8 s8; short4v h[2]; };

static __device__ __forceinline__ float fexp2(float x) {
    return __builtin_amdgcn_exp2f(x);   // v_exp_f32
}

static __device__ __forceinline__ unsigned int pk2(float lo, float hi) {
    __hip_bfloat16 a = __float2bfloat16(lo), b = __float2bfloat16(hi);
    unsigned short au = *(unsigned short*)&a, bu = *(unsigned short*)&b;
    return (unsigned int)au | ((unsigned int)bu << 16);
}

// ---- merged prep: [0,1056) fold Wq*W -> WqT bf16 (+bq2); [1056,4128) transpose Wk/Wv/Wo;
//      [4128,10272) convert queries/keys/values fp32 -> bf16 ----
__global__ __launch_bounds__(256) void prep_all_kernel(
    const float* __restrict__ Wq, const float* __restrict__ bq, const float* __restrict__ W,
    __hip_bfloat16* __restrict__ WqT, float* __restrict__ bq2,
    const float* __restrict__ Wk, const float* __restrict__ Wv, const float* __restrict__ Wo,
    __hip_bfloat16* __restrict__ WkT, __hip_bfloat16* __restrict__ WvT,
    __hip_bfloat16* __restrict__ WoT,
    const float* __restrict__ q, const float* __restrict__ k, const float* __restrict__ v,
    __hip_bfloat16* __restrict__ oq, __hip_bfloat16* __restrict__ ok,
    __hip_bfloat16* __restrict__ ov) {
    const int blk = blockIdx.x;
    const int t = threadIdx.x;

    if (blk < 1056) {
        const int c0 = (blk & 31) * 32;
        const int yy = blk >> 5;             // 0..32
        const int h = c0 >> 6, j0 = c0 & 63;
        if (yy == 32) {
            if (t < 32) {
                int col = c0 + t, j = col & 63;
                float s = 0.f;
#pragma unroll
                for (int d = 0; d < DH; ++d) s += bq[h * DH + d] * W[d * DH + j];
                bq2[col] = s * LOG2E;
            }
            return;
        }
        const int r0 = yy * 32;
        __shared__ float sWq[32][68];
        __shared__ float sW[64][36];
        __shared__ float sOut[32][33];
        {
            int lr = t >> 3, lc8 = (t & 7) * 8;
            const float* src = Wq + (size_t)(r0 + lr) * D_MODEL + h * DH + lc8;
            *(float4*)&sWq[lr][lc8]     = *(const float4*)(src);
            *(float4*)&sWq[lr][lc8 + 4] = *(const float4*)(src + 4);
            int d = t >> 2, c8 = (t & 3) * 8;
            const float* wsrc = W + (size_t)d * DH + j0 + c8;
            *(float4*)&sW[d][c8]     = *(const float4*)(wsrc);
            *(float4*)&sW[d][c8 + 4] = *(const float4*)(wsrc + 4);
        }
        __syncthreads();
        {
            int col_loc = t & 31, rq = t >> 5;
            float acc0 = 0.f, acc1 = 0.f, acc2 = 0.f, acc3 = 0.f;
#pragma unroll
            for (int d = 0; d < 64; ++d) {
                float wv = sW[d][col_loc];
                acc0 += sWq[rq * 4 + 0][d] * wv;
                acc1 += sWq[rq * 4 + 1][d] * wv;
                acc2 += sWq[rq * 4 + 2][d] * wv;
                acc3 += sWq[rq * 4 + 3][d] * wv;
            }
            sOut[col_loc][rq * 4 + 0] = acc0 * LOG2E;
            sOut[col_loc][rq * 4 + 1] = acc1 * LOG2E;
            sOut[col_loc][rq * 4 + 2] = acc2 * LOG2E;
            sOut[col_loc][rq * 4 + 3] = acc3 * LOG2E;
        }
        __syncthreads();
        {
            int orow = t >> 3, oc4 = (t & 7) * 4;
            __hip_bfloat16 o4[4];
#pragma unroll
            for (int i = 0; i < 4; ++i) o4[i] = __float2bfloat16(sOut[orow][oc4 + i]);
            *(short4*)(WqT + (size_t)(c0 + orow) * D_MODEL + r0 + oc4) = *(short4*)o4;
        }
    } else if (blk < 4128) {
        __shared__ float sT[32][33];
        int r = blk - 1056;
        int z = r >> 10; r &= 1023;
        const float* Win = (z == 0) ? Wk : (z == 1) ? Wv : Wo;
        __hip_bfloat16* Wt = (z == 0) ? WkT : (z == 1) ? WvT : WoT;
        int n0 = (r & 31) * 32, k0 = (r >> 5) * 32;
        int tx = t & 31, ty = t >> 5;
#pragma unroll
        for (int i = 0; i < 4; ++i)
            sT[ty + i * 8][tx] = Win[(size_t)(k0 + ty + i * 8) * D_MODEL + n0 + tx];
        __syncthreads();
#pragma unroll
        for (int i = 0; i < 4; ++i)
            Wt[(size_t)(n0 + ty + i * 8) * D_MODEL + k0 + tx] =
                __float2bfloat16(sT[tx][ty + i * 8]);
    } else {
        int idx = blk - 4128;                    // 0..6143
        int z = idx >> 11;
        int i = (idx & 2047) * 256 + t;
        const float* in = (z == 0) ? q : (z == 1) ? k : v;
        __hip_bfloat16* out = (z == 0) ? oq : (z == 1) ? ok : ov;
        float4 a = *(const float4*)(in + (size_t)i * 8);
        float4 b = *(const float4*)(in + (size_t)i * 8 + 4);
        __hip_bfloat16 o[8];
        o[0] = __float2bfloat16(a.x); o[1] = __float2bfloat16(a.y);
        o[2] = __float2bfloat16(a.z); o[3] = __float2bfloat16(a.w);
        o[4] = __float2bfloat16(b.x); o[5] = __float2bfloat16(b.y);
        o[6] = __float2bfloat16(b.z); o[7] = __float2bfloat16(b.w);
        *(short8*)(out + (size_t)i * 8) = *(short8*)o;
    }
}

// ============ GEMM core (128x128, BK=32, 2-phase dbuf) + T1 bijective XCD swizzle ==========
#define GEMM_CORE(A_, BT_)                                                                  \
    __shared__ __hip_bfloat16 sA[2][128 * 32];                                              \
    __shared__ __hip_bfloat16 sB[2][128 * 32];                                              \
    const int t = threadIdx.x;                                                              \
    const int lane = t & 63, w = t >> 6;                                                    \
    const int g = lane >> 4, li = lane & 15;                                                \
    const int lin = blockIdx.y * 8 + blockIdx.x;                                            \
    const int ob = (lin & 7) * 32 + (lin >> 3);                                             \
    const int r0 = (ob >> 3) * 128, c0 = (ob & 7) * 128;                                    \
    const int wr = (w >> 1) * 64, wc = (w & 1) * 64;                                        \
    f32x4 acc[4][4] = {};                                                                   \
    auto stage = [&](int bb, int k0) {                                                      \
        _Pragma("unroll")                                                                   \
        for (int i = 0; i < 2; ++i) {                                                       \
            int o = (i * 4 + w) * 1024 + lane * 16;                                         \
            int row = o >> 6, ce = (o & 63) >> 1;                                           \
            __builtin_amdgcn_global_load_lds(AS1C(A_ + (size_t)(r0 + row) * 1024 + k0 + ce),\
                                             AS3((char*)sA[bb] + (i * 4 + w) * 1024), 16, 0, 0); \
            __builtin_amdgcn_global_load_lds(AS1C(BT_ + (size_t)(c0 + row) * 1024 + k0 + ce),\
                                             AS3((char*)sB[bb] + (i * 4 + w) * 1024), 16, 0, 0); \
        }                                                                                   \
    };                                                                                      \
    stage(0, 0);                                                                            \
    asm volatile("s_waitcnt vmcnt(0)" ::: "memory");                                        \
    __syncthreads();                                                                        \
    int cur = 0;                                                                            \
    for (int k0 = 0; k0 < 1024; k0 += 32) {                                                 \
        if (k0 + 32 < 1024) stage(cur ^ 1, k0 + 32);                                        \
        short8 af[4], bf[4];                                                                \
        _Pragma("unroll")                                                                   \
        for (int m = 0; m < 4; ++m)                                                         \
            af[m] = *(const short8*)(sA[cur] + (wr + m * 16 + li) * 32 + g * 8);            \
        _Pragma("unroll")                                                                   \
        for (int n = 0; n < 4; ++n)                                                         \
            bf[n] = *(const short8*)(sB[cur] + (wc + n * 16 + li) * 32 + g * 8);            \
        _Pragma("unroll")                                                                   \
        for (int m = 0; m < 4; ++m)                                                         \
            _Pragma("unroll")                                                               \
            for (int n = 0; n < 4; ++n)                                                     \
                acc[m][n] = __builtin_amdgcn_mfma_f32_16x16x32_bf16(af[m], bf[n], acc[m][n], 0, 0, 0); \
        asm volatile("s_waitcnt vmcnt(0)" ::: "memory");                                    \
        __syncthreads();                                                                    \
        cur ^= 1;                                                                           \
    }

// ---------------- QKV projections, one launch (grid.z selects which) ----------------
// z=2 (V) writes Vt in the PV-PERMUTED layout: within each 128-key block,
// key s (= 16ks+4g2+rr) is stored at p = g2*32 + ks*4 + rr.
__global__ __launch_bounds__(256) void gemm_qkv_kernel(
    const __hip_bfloat16* __restrict__ Xq, const __hip_bfloat16* __restrict__ Xk,
    const __hip_bfloat16* __restrict__ Xv,
    const __hip_bfloat16* __restrict__ WqT, const __hip_bfloat16* __restrict__ WkT,
    const __hip_bfloat16* __restrict__ WvT,
    const float* __restrict__ bq2, const float* __restrict__ bk, const float* __restrict__ bv,
    __hip_bfloat16* __restrict__ Qp, __hip_bfloat16* __restrict__ Kp,
    __hip_bfloat16* __restrict__ Vt) {
    const int z = blockIdx.z;
    const __hip_bfloat16* A  = (z == 0) ? Xq  : (z == 1) ? Xk  : Xv;
    const __hip_bfloat16* BT = (z == 0) ? WqT : (z == 1) ? WkT : WvT;
    const float* bias        = (z == 0) ? bq2 : (z == 1) ? bk  : bv;
    __hip_bfloat16* C        = (z == 0) ? Qp  : (z == 1) ? Kp  : Vt;

    GEMM_CORE(A, BT)

#pragma unroll
    for (int m = 0; m < 4; ++m) {
#pragma unroll
        for (int n = 0; n < 4; ++n) {
            int col = c0 + wc + n * 16 + li;
            float bs = bias[col];
            int row0 = r0 + wr + m * 16 + g * 4;
            int h = col >> 6, d = col & 63;
            if (z == 2) {
                int b = row0 >> 11, s0 = row0 & 2047;
                int sp = (s0 & ~127) | (((s0 >> 2) & 3) << 5) | (((s0 >> 4) & 7) << 2);
                __hip_bfloat16 o4[4];
#pragma unroll
                for (int r = 0; r < 4; ++r) o4[r] = __float2bfloat16(acc[m][n][r] + bs);
                *(short4*)(C + (((size_t)(b * NHEADS + h)) * DH + d) * SEQ + sp) = *(short4*)o4;
            } else {
#pragma unroll
                for (int r = 0; r < 4; ++r) {
                    int row = row0 + r;
                    int b = row >> 11, s = row & 2047;
                    C[(((size_t)(b * NHEADS + h)) * SEQ + s) * DH + d] =
                        __float2bfloat16(acc[m][n][r] + bs);
                }
            }
        }
    }
}

// ---------------- output projection (fp32 out) ----------------
__global__ __launch_bounds__(256) void gemm_out_kernel(
    const __hip_bfloat16* __restrict__ A, const __hip_bfloat16* __restrict__ BT,
    const float* __restrict__ bias, float* __restrict__ C) {
    GEMM_CORE(A, BT)
#pragma unroll
    for (int m = 0; m < 4; ++m) {
#pragma unroll
        for (int n = 0; n < 4; ++n) {
            int col = c0 + wc + n * 16 + li;
            float bs = bias[col];
            int row0 = r0 + wr + m * 16 + g * 4;
#pragma unroll
            for (int r = 0; r < 4; ++r)
                C[(size_t)(row0 + r) * D_MODEL + col] = acc[m][n][r] + bs;
        }
    }
}

// ------- Vsum[bh][dh] = sum_{s >= loop_end_b} Vt[bh][dh][s]  (f32), 128-granular -------
__global__ __launch_bounds__(256) void vsum_kernel(const __hip_bfloat16* __restrict__ Vt,
                                                   const int* __restrict__ thresholds,
                                                   float* __restrict__ Vsum) {
    int bh = blockIdx.x, b = bh >> 4;
    int thresh = thresholds[b];
    int loop_end = min(SEQ, ((thresh + 127) >> 7) << 7);
    int t = threadIdx.x;
    int dh = t >> 2, sub = t & 3;
    const __hip_bfloat16* row = Vt + ((size_t)bh * DH + dh) * SEQ;
    float s = 0.f;
    for (int s0 = loop_end + sub * 8; s0 < SEQ; s0 += 32) {
        short8 v = *(const short8*)(row + s0);
#pragma unroll
        for (int j = 0; j < 8; ++j) {
            unsigned short us = (unsigned short)v[j];
            s += __bfloat162float(*(__hip_bfloat16*)&us);
        }
    }
    s += __shfl_xor(s, 1);
    s += __shfl_xor(s, 2);
    if (sub == 0) Vsum[bh * DH + dh] = s;
}

// ----- flash MFMA attention: KVBLK=128, 4 waves x 32 q (mq=2), fragment-reuse x2 -----
// LDS reads per unit work HALVED: 16 K reads feed 32 QK MFMA (2 Q B-frags);
// 16 V b128 reads feed 64 PV MFMA (shared across mq). 128 q/block, 512 blocks, 2/CU.
// Qp/Kp: [B*H][S][DH] bf16 (Q pre-scaled log2e). Vt: [B*H][DH][S] bf16 block-permuted.
__global__ __launch_bounds__(256, 2) void attn_mfma_kernel(
    const __hip_bfloat16* __restrict__ Qp,
    const __hip_bfloat16* __restrict__ Kp,
    const __hip_bfloat16* __restrict__ Vt,
    const int* __restrict__ thresholds,
    const float* __restrict__ Vsum,
    __hip_bfloat16* __restrict__ AO) {
    __shared__ char lds[65536];   // sK[2][16KB] | sVT[2][16KB]
    char* sK  = lds;
    char* sVT = lds + 32768;

    const int t = threadIdx.x, lane = t & 63, w = t >> 6;   // w in {0..3}
    const int g = lane >> 4, li = lane & 15;
    const int bh = blockIdx.x, b = bh >> 4, h = bh & 15;
    const int q0 = blockIdx.y * 128;
    const int thresh = thresholds[b];
    const int loop_end = min(SEQ, ((thresh + 127) >> 7) << 7);
    const __hip_bfloat16* Qb = Qp + (size_t)bh * SEQ * DH;
    const __hip_bfloat16* Kb = Kp + (size_t)bh * SEQ * DH;
    const __hip_bfloat16* Vb = Vt + (size_t)bh * DH * SEQ;

    // Q as B-fragments: wave owns q rows q0 + w*32 + mq*16 + li
    short8 qf[2][2];
#pragma unroll
    for (int mq = 0; mq < 2; ++mq)
#pragma unroll
        for (int kb = 0; kb < 2; ++kb)
            qf[mq][kb] = *(const short8*)(Qb + (size_t)(q0 + w * 32 + mq * 16 + li) * DH +
                                          kb * 32 + g * 8);

    // O^T accumulators: col=q(li), row=dh=16n+4g+rr
    f32x4 Oacc[2][4] = {};
    float mrun[2] = {NEG_INF, NEG_INF};
    float lpart[2] = {0.f, 0.f};

    auto stageK = [&](int bb, int kv) {
#pragma unroll
        for (int i = 0; i < 4; ++i) {
            int o = i * 4096 + w * 1024 + lane * 16;
            int key = o >> 7, slot = (o & 127) >> 4;
            __builtin_amdgcn_global_load_lds(
                AS1C(Kb + (size_t)(kv + key) * DH + ((slot ^ (key & 7)) << 3)),
                AS3(sK + bb * 16384 + i * 4096 + w * 1024), 16, 0, 0);
        }
    };
    auto stageV = [&](int bb, int kv) {
#pragma unroll
        for (int i = 0; i < 4; ++i) {
            int o = i * 4096 + w * 1024 + lane * 16;
            int dh = o >> 8, slot = (o & 255) >> 4;
            __builtin_amdgcn_global_load_lds(
                AS1C(Vb + (size_t)dh * SEQ + kv + ((slot ^ (dh & 15)) << 3)),
                AS3(sVT + bb * 16384 + i * 4096 + w * 1024), 16, 0, 0);
        }
    };

    stageK(0, 0); stageV(0, 0);
    asm volatile("s_waitcnt vmcnt(0)" ::: "memory");
    __syncthreads();

    int cur = 0;
    for (int kv0 = 0; kv0 < loop_end; kv0 += 128) {
        int nxt = kv0 + 128;
        if (nxt < loop_end) { stageK(cur ^ 1, nxt); stageV(cur ^ 1, nxt); }

        // ---- QK^T swapped: each kf read feeds BOTH mq sub-tiles ----
        f32x4 S[2][8] = {};
        __builtin_amdgcn_s_setprio(1);
#pragma unroll
        for (int kb = 0; kb < 2; ++kb) {
            short8 kf[8];
#pragma unroll
            for (int n = 0; n < 8; ++n) {
                int key = 16 * n + li;
                kf[n] = *(const short8*)(sK + cur * 16384 + key * 128 +
                                         (((4 * kb + g) ^ (key & 7)) << 4));
            }
#pragma unroll
            for (int n = 0; n < 8; ++n) {
                S[0][n] = __builtin_amdgcn_mfma_f32_16x16x32_bf16(kf[n], qf[0][kb], S[0][n], 0, 0, 0);
                S[1][n] = __builtin_amdgcn_mfma_f32_16x16x32_bf16(kf[n], qf[1][kb], S[1][n], 0, 0, 0);
            }
        }
        __builtin_amdgcn_s_setprio(0);

        if (kv0 + 128 > thresh) {
            // straddle tile only: key = kv0 + 16n + 4g + rr
            int tr = thresh - kv0 - 4 * g;
#pragma unroll
            for (int n = 0; n < 8; ++n)
#pragma unroll
                for (int rr = 0; rr < 4; ++rr)
                    if (16 * n + rr >= tr) { S[0][n][rr] = MASKB2; S[1][n][rr] = MASKB2; }
        }

        // per-lane row max per mq (lane owns q=li); row-uniform via 2 shuffles
        float pmax[2];
#pragma unroll
        for (int mq = 0; mq < 2; ++mq) {
            float mx = S[mq][0][0];
#pragma unroll
            for (int n = 0; n < 8; ++n)
#pragma unroll
                for (int rr = 0; rr < 4; ++rr) mx = fmaxf(mx, S[mq][n][rr]);
            mx = fmaxf(mx, __shfl_xor(mx, 16));
            mx = fmaxf(mx, __shfl_xor(mx, 32));
            pmax[mq] = mx;
        }

        // defer-max (T13)
        bool need = (pmax[0] > mrun[0] + DEFER_THR) || (pmax[1] > mrun[1] + DEFER_THR);
        if (__any(need)) {
#pragma unroll
            for (int mq = 0; mq < 2; ++mq) {
                float mn = fmaxf(mrun[mq], pmax[mq]);
                float alpha = fexp2(mrun[mq] - mn);
                lpart[mq] *= alpha;
#pragma unroll
                for (int n = 0; n < 4; ++n)
#pragma unroll
                    for (int rr = 0; rr < 4; ++rr) Oacc[mq][n][rr] *= alpha;
                mrun[mq] = mn;
            }
        }

        // exp2 + per-lane partial rowsum + pack into PV B-fragments
        short4v pb[2][8];
#pragma unroll
        for (int mq = 0; mq < 2; ++mq)
#pragma unroll
            for (int n = 0; n < 8; ++n) {
#pragma unroll
                for (int rr = 0; rr < 4; ++rr) {
                    float p = fexp2(S[mq][n][rr] - mrun[mq]);
                    S[mq][n][rr] = p;
                    lpart[mq] += p;
                }
                PB u;
                u.u[0] = pk2(S[mq][n][0], S[mq][n][1]);
                u.u[1] = pk2(S[mq][n][2], S[mq][n][3]);
                pb[mq][n] = u.s4;
            }

        // ---- PV: each V b128 read feeds 4 MFMAs (2 halves x 2 mq) ----
        __builtin_amdgcn_s_setprio(1);
#pragma unroll
        for (int u = 0; u < 4; ++u) {
            int slot = 4 * g + u;
#pragma unroll
            for (int n = 0; n < 4; ++n) {
                int dh = 16 * n + li;
                VU vu;
                vu.s8 = *(const short8*)(sVT + cur * 16384 + dh * 256 +
                                         ((slot ^ (dh & 15)) << 4));
                Oacc[0][n] = __builtin_amdgcn_mfma_f32_16x16x16bf16_1k(vu.h[0], pb[0][2 * u],
                                                                       Oacc[0][n], 0, 0, 0);
                Oacc[0][n] = __builtin_amdgcn_mfma_f32_16x16x16bf16_1k(vu.h[1], pb[0][2 * u + 1],
                                                                       Oacc[0][n], 0, 0, 0);
                Oacc[1][n] = __builtin_amdgcn_mfma_f32_16x16x16bf16_1k(vu.h[0], pb[1][2 * u],
                                                                       Oacc[1][n], 0, 0, 0);
                Oacc[1][n] = __builtin_amdgcn_mfma_f32_16x16x16bf16_1k(vu.h[1], pb[1][2 * u + 1],
                                                                       Oacc[1][n], 0, 0, 0);
            }
        }
        __builtin_amdgcn_s_setprio(0);

        asm volatile("s_waitcnt vmcnt(0)" ::: "memory");
        __syncthreads();
        cur ^= 1;
    }

    // combine per-lane partial rowsums once
    float lrun[2];
#pragma unroll
    for (int mq = 0; mq < 2; ++mq) {
        float l = lpart[mq];
        l += __shfl_xor(l, 16);
        l += __shfl_xor(l, 32);
        lrun[mq] = l;
    }

    // ---- analytic masked tail: keys in [loop_end, SEQ) all have score MASKB2 ----
    int nmask = SEQ - loop_end;
    if (nmask > 0) {
        const float* vs = Vsum + bh * DH;
        f32x4 vsf[4];
#pragma unroll
        for (int n = 0; n < 4; ++n) vsf[n] = *(const f32x4*)(vs + 16 * n + 4 * g);
#pragma unroll
        for (int mq = 0; mq < 2; ++mq) {
            float pu = fexp2(MASKB2 - mrun[mq]);
            lrun[mq] += (float)nmask * pu;
#pragma unroll
            for (int n = 0; n < 4; ++n)
#pragma unroll
                for (int rr = 0; rr < 4; ++rr) Oacc[mq][n][rr] += pu * vsf[n][rr];
        }
    }

    // ---- epilogue: normalize, write bf16 (8B stores) ----
#pragma unroll
    for (int mq = 0; mq < 2; ++mq) {
        float linv = 1.0f / lrun[mq];
        int q = q0 + w * 32 + mq * 16 + li;
#pragma unroll
        for (int n = 0; n < 4; ++n) {
            __hip_bfloat16 o4[4];
#pragma unroll
            for (int rr = 0; rr < 4; ++rr) o4[rr] = __float2bfloat16(Oacc[mq][n][rr] * linv);
            *(short4*)(AO + (size_t)(b * SEQ + q) * D_MODEL + h * DH + 16 * n + 4 * g) =
                *(short4*)o4;
        }
    }
}

extern "C" void kernel_launch(void* const* d_in, const int* in_sizes, int n_in,
                              void* d_out, int out_size, void* d_ws, size_t ws_size,
                              hipStream_t stream) {
    const float* queries    = (const float*)d_in[0];
    const float* keys       = (const float*)d_in[1];
    const float* values     = (const float*)d_in[2];
    const int*   thresholds = (const int*)d_in[3];
    const float* Wq = (const float*)d_in[4];
    const float* bq = (const float*)d_in[5];
    const float* Wk = (const float*)d_in[6];
    const float* bk = (const float*)d_in[7];
    const float* Wv = (const float*)d_in[8];
    const float* bv = (const float*)d_in[9];
    const float* W  = (const float*)d_in[10];
    const float* Wo = (const float*)d_in[11];
    const float* bo = (const float*)d_in[12];
    float* out = (float*)d_out;

    char* wsb = (char*)d_ws;
    float* bq2  = (float*)wsb;                         // 4 KB
    float* Vsum = (float*)(wsb + 4096);                // 8 KB
    __hip_bfloat16* XqB = (__hip_bfloat16*)(wsb + 16384);
    __hip_bfloat16* XkB = XqB + (1 << 22);
    __hip_bfloat16* XvB = XkB + (1 << 22);
    __hip_bfloat16* WqT = XvB + (1 << 22);
    __hip_bfloat16* WkT = WqT + (1 << 20);
    __hip_bfloat16* WvT = WkT + (1 << 20);
    __hip_bfloat16* WoT = WvT + (1 << 20);
    __hip_bfloat16* QpB = WoT + (1 << 20);
    __hip_bfloat16* KpB = QpB + (1 << 22);
    __hip_bfloat16* VtB = KpB + (1 << 22);
    __hip_bfloat16* AOB = XqB;   // alias: XqB dead after Q projection

    prep_all_kernel<<<10272, 256, 0, stream>>>(Wq, bq, W, WqT, bq2,
                                               Wk, Wv, Wo, WkT, WvT, WoT,
                                               queries, keys, values, XqB, XkB, XvB);

    gemm_qkv_kernel<<<dim3(8, 32, 3), 256, 0, stream>>>(XqB, XkB, XvB, WqT, WkT, WvT,
                                                        bq2, bk, bv, QpB, KpB, VtB);
    vsum_kernel<<<32, 256, 0, stream>>>(VtB, thresholds, Vsum);

    attn_mfma_kernel<<<dim3(32, 16), 256, 0, stream>>>(QpB, KpB, VtB, thresholds, Vsum, AOB);

    gemm_out_kernel<<<dim3(8, 32), 256, 0, stream>>>(AOB, WoT, bo, out);
}

// Round 22
// 146.013 us; speedup vs baseline: 1.0360x; 1.0360x over previous
//
#include <hip/hip_runtime.h>
#include <hip/hip_bf16.h>

#define D_MODEL 1024
#define NHEADS  16
#define DH      64
#define SEQ     2048
#define BATCH   2

#define LOG2E 1.4426950408889634f
#define MASKB2 (-1e-6f * LOG2E)   // mask value in exp2 domain
#define DEFER_THR 11.5456f        // 8 * log2e
#define NEG_INF (-__builtin_inff())

typedef __attribute__((ext_vector_type(8))) short short8;
typedef __attribute__((ext_vector_type(4))) short short4v;
typedef __attribute__((ext_vector_type(4))) float f32x4;

#define AS1C(p) ((const __attribute__((address_space(1))) void*)(p))
#define AS3(p)  ((__attribute__((address_space(3))) void*)(p))

union PB { short4v s4; unsigned int u[2]; };
union VU { short8 s8; short4v h[2]; };

static __device__ __forceinline__ float fexp2(float x) {
    return __builtin_amdgcn_exp2f(x);   // v_exp_f32
}

static __device__ __forceinline__ unsigned int pk2(float lo, float hi) {
    __hip_bfloat16 a = __float2bfloat16(lo), b = __float2bfloat16(hi);
    unsigned short au = *(unsigned short*)&a, bu = *(unsigned short*)&b;
    return (unsigned int)au | ((unsigned int)bu << 16);
}

// ---- merged prep: [0,1056) fold Wq*W -> WqT bf16 (+bq2); [1056,4128) transpose Wk/Wv/Wo;
//      [4128,10272) convert queries/keys/values fp32 -> bf16 ----
__global__ __launch_bounds__(256) void prep_all_kernel(
    const float* __restrict__ Wq, const float* __restrict__ bq, const float* __restrict__ W,
    __hip_bfloat16* __restrict__ WqT, float* __restrict__ bq2,
    const float* __restrict__ Wk, const float* __restrict__ Wv, const float* __restrict__ Wo,
    __hip_bfloat16* __restrict__ WkT, __hip_bfloat16* __restrict__ WvT,
    __hip_bfloat16* __restrict__ WoT,
    const float* __restrict__ q, const float* __restrict__ k, const float* __restrict__ v,
    __hip_bfloat16* __restrict__ oq, __hip_bfloat16* __restrict__ ok,
    __hip_bfloat16* __restrict__ ov) {
    const int blk = blockIdx.x;
    const int t = threadIdx.x;

    if (blk < 1056) {
        const int c0 = (blk & 31) * 32;
        const int yy = blk >> 5;             // 0..32
        const int h = c0 >> 6, j0 = c0 & 63;
        if (yy == 32) {
            if (t < 32) {
                int col = c0 + t, j = col & 63;
                float s = 0.f;
#pragma unroll
                for (int d = 0; d < DH; ++d) s += bq[h * DH + d] * W[d * DH + j];
                bq2[col] = s * LOG2E;
            }
            return;
        }
        const int r0 = yy * 32;
        __shared__ float sWq[32][68];
        __shared__ float sW[64][36];
        __shared__ float sOut[32][33];
        {
            int lr = t >> 3, lc8 = (t & 7) * 8;
            const float* src = Wq + (size_t)(r0 + lr) * D_MODEL + h * DH + lc8;
            *(float4*)&sWq[lr][lc8]     = *(const float4*)(src);
            *(float4*)&sWq[lr][lc8 + 4] = *(const float4*)(src + 4);
            int d = t >> 2, c8 = (t & 3) * 8;
            const float* wsrc = W + (size_t)d * DH + j0 + c8;
            *(float4*)&sW[d][c8]     = *(const float4*)(wsrc);
            *(float4*)&sW[d][c8 + 4] = *(const float4*)(wsrc + 4);
        }
        __syncthreads();
        {
            int col_loc = t & 31, rq = t >> 5;
            float acc0 = 0.f, acc1 = 0.f, acc2 = 0.f, acc3 = 0.f;
#pragma unroll
            for (int d = 0; d < 64; ++d) {
                float wv = sW[d][col_loc];
                acc0 += sWq[rq * 4 + 0][d] * wv;
                acc1 += sWq[rq * 4 + 1][d] * wv;
                acc2 += sWq[rq * 4 + 2][d] * wv;
                acc3 += sWq[rq * 4 + 3][d] * wv;
            }
            sOut[col_loc][rq * 4 + 0] = acc0 * LOG2E;
            sOut[col_loc][rq * 4 + 1] = acc1 * LOG2E;
            sOut[col_loc][rq * 4 + 2] = acc2 * LOG2E;
            sOut[col_loc][rq * 4 + 3] = acc3 * LOG2E;
        }
        __syncthreads();
        {
            int orow = t >> 3, oc4 = (t & 7) * 4;
            __hip_bfloat16 o4[4];
#pragma unroll
            for (int i = 0; i < 4; ++i) o4[i] = __float2bfloat16(sOut[orow][oc4 + i]);
            *(short4*)(WqT + (size_t)(c0 + orow) * D_MODEL + r0 + oc4) = *(short4*)o4;
        }
    } else if (blk < 4128) {
        __shared__ float sT[32][33];
        int r = blk - 1056;
        int z = r >> 10; r &= 1023;
        const float* Win = (z == 0) ? Wk : (z == 1) ? Wv : Wo;
        __hip_bfloat16* Wt = (z == 0) ? WkT : (z == 1) ? WvT : WoT;
        int n0 = (r & 31) * 32, k0 = (r >> 5) * 32;
        int tx = t & 31, ty = t >> 5;
#pragma unroll
        for (int i = 0; i < 4; ++i)
            sT[ty + i * 8][tx] = Win[(size_t)(k0 + ty + i * 8) * D_MODEL + n0 + tx];
        __syncthreads();
#pragma unroll
        for (int i = 0; i < 4; ++i)
            Wt[(size_t)(n0 + ty + i * 8) * D_MODEL + k0 + tx] =
                __float2bfloat16(sT[tx][ty + i * 8]);
    } else {
        int idx = blk - 4128;                    // 0..6143
        int z = idx >> 11;
        int i = (idx & 2047) * 256 + t;
        const float* in = (z == 0) ? q : (z == 1) ? k : v;
        __hip_bfloat16* out = (z == 0) ? oq : (z == 1) ? ok : ov;
        float4 a = *(const float4*)(in + (size_t)i * 8);
        float4 b = *(const float4*)(in + (size_t)i * 8 + 4);
        __hip_bfloat16 o[8];
        o[0] = __float2bfloat16(a.x); o[1] = __float2bfloat16(a.y);
        o[2] = __float2bfloat16(a.z); o[3] = __float2bfloat16(a.w);
        o[4] = __float2bfloat16(b.x); o[5] = __float2bfloat16(b.y);
        o[6] = __float2bfloat16(b.z); o[7] = __float2bfloat16(b.w);
        *(short8*)(out + (size_t)i * 8) = *(short8*)o;
    }
}

// ============ GEMM core (128x128, BK=32, 2-phase dbuf) + T1 bijective XCD swizzle ==========
#define GEMM_CORE(A_, BT_)                                                                  \
    __shared__ __hip_bfloat16 sA[2][128 * 32];                                              \
    __shared__ __hip_bfloat16 sB[2][128 * 32];                                              \
    const int t = threadIdx.x;                                                              \
    const int lane = t & 63, w = t >> 6;                                                    \
    const int g = lane >> 4, li = lane & 15;                                                \
    const int lin = blockIdx.y * 8 + blockIdx.x;                                            \
    const int ob = (lin & 7) * 32 + (lin >> 3);                                             \
    const int r0 = (ob >> 3) * 128, c0 = (ob & 7) * 128;                                    \
    const int wr = (w >> 1) * 64, wc = (w & 1) * 64;                                        \
    f32x4 acc[4][4] = {};                                                                   \
    auto stage = [&](int bb, int k0) {                                                      \
        _Pragma("unroll")                                                                   \
        for (int i = 0; i < 2; ++i) {                                                       \
            int o = (i * 4 + w) * 1024 + lane * 16;                                         \
            int row = o >> 6, ce = (o & 63) >> 1;                                           \
            __builtin_amdgcn_global_load_lds(AS1C(A_ + (size_t)(r0 + row) * 1024 + k0 + ce),\
                                             AS3((char*)sA[bb] + (i * 4 + w) * 1024), 16, 0, 0); \
            __builtin_amdgcn_global_load_lds(AS1C(BT_ + (size_t)(c0 + row) * 1024 + k0 + ce),\
                                             AS3((char*)sB[bb] + (i * 4 + w) * 1024), 16, 0, 0); \
        }                                                                                   \
    };                                                                                      \
    stage(0, 0);                                                                            \
    asm volatile("s_waitcnt vmcnt(0)" ::: "memory");                                        \
    __syncthreads();                                                                        \
    int cur = 0;                                                                            \
    for (int k0 = 0; k0 < 1024; k0 += 32) {                                                 \
        if (k0 + 32 < 1024) stage(cur ^ 1, k0 + 32);                                        \
        short8 af[4], bf[4];                                                                \
        _Pragma("unroll")                                                                   \
        for (int m = 0; m < 4; ++m)                                                         \
            af[m] = *(const short8*)(sA[cur] + (wr + m * 16 + li) * 32 + g * 8);            \
        _Pragma("unroll")                                                                   \
        for (int n = 0; n < 4; ++n)                                                         \
            bf[n] = *(const short8*)(sB[cur] + (wc + n * 16 + li) * 32 + g * 8);            \
        _Pragma("unroll")                                                                   \
        for (int m = 0; m < 4; ++m)                                                         \
            _Pragma("unroll")                                                               \
            for (int n = 0; n < 4; ++n)                                                     \
                acc[m][n] = __builtin_amdgcn_mfma_f32_16x16x32_bf16(af[m], bf[n], acc[m][n], 0, 0, 0); \
        asm volatile("s_waitcnt vmcnt(0)" ::: "memory");                                    \
        __syncthreads();                                                                    \
        cur ^= 1;                                                                           \
    }

// ---------------- QKV projections, one launch (grid.z selects which) ----------------
// z=2 (V) writes Vt in the PV-PERMUTED layout: within each 128-key block,
// key s (= 16ks+4g2+rr) is stored at p = g2*32 + ks*4 + rr, so PV A-fragments
// (keys 16ks+4g+{0..3} for consecutive ks pairs) are 16B-contiguous.
__global__ __launch_bounds__(256) void gemm_qkv_kernel(
    const __hip_bfloat16* __restrict__ Xq, const __hip_bfloat16* __restrict__ Xk,
    const __hip_bfloat16* __restrict__ Xv,
    const __hip_bfloat16* __restrict__ WqT, const __hip_bfloat16* __restrict__ WkT,
    const __hip_bfloat16* __restrict__ WvT,
    const float* __restrict__ bq2, const float* __restrict__ bk, const float* __restrict__ bv,
    __hip_bfloat16* __restrict__ Qp, __hip_bfloat16* __restrict__ Kp,
    __hip_bfloat16* __restrict__ Vt) {
    const int z = blockIdx.z;
    const __hip_bfloat16* A  = (z == 0) ? Xq  : (z == 1) ? Xk  : Xv;
    const __hip_bfloat16* BT = (z == 0) ? WqT : (z == 1) ? WkT : WvT;
    const float* bias        = (z == 0) ? bq2 : (z == 1) ? bk  : bv;
    __hip_bfloat16* C        = (z == 0) ? Qp  : (z == 1) ? Kp  : Vt;

    GEMM_CORE(A, BT)

#pragma unroll
    for (int m = 0; m < 4; ++m) {
#pragma unroll
        for (int n = 0; n < 4; ++n) {
            int col = c0 + wc + n * 16 + li;
            float bs = bias[col];
            int row0 = r0 + wr + m * 16 + g * 4;
            int h = col >> 6, d = col & 63;
            if (z == 2) {
                int b = row0 >> 11, s0 = row0 & 2047;
                // permute within 128-key block: s0 = blk*128 + 16*ks + 4*g2 ->
                // sp = blk*128 + g2*32 + ks*4
                int sp = (s0 & ~127) | (((s0 >> 2) & 3) << 5) | (((s0 >> 4) & 7) << 2);
                __hip_bfloat16 o4[4];
#pragma unroll
                for (int r = 0; r < 4; ++r) o4[r] = __float2bfloat16(acc[m][n][r] + bs);
                *(short4*)(C + (((size_t)(b * NHEADS + h)) * DH + d) * SEQ + sp) = *(short4*)o4;
            } else {
#pragma unroll
                for (int r = 0; r < 4; ++r) {
                    int row = row0 + r;
                    int b = row >> 11, s = row & 2047;
                    C[(((size_t)(b * NHEADS + h)) * SEQ + s) * DH + d] =
                        __float2bfloat16(acc[m][n][r] + bs);
                }
            }
        }
    }
}

// ---------------- output projection (fp32 out) ----------------
__global__ __launch_bounds__(256) void gemm_out_kernel(
    const __hip_bfloat16* __restrict__ A, const __hip_bfloat16* __restrict__ BT,
    const float* __restrict__ bias, float* __restrict__ C) {
    GEMM_CORE(A, BT)
#pragma unroll
    for (int m = 0; m < 4; ++m) {
#pragma unroll
        for (int n = 0; n < 4; ++n) {
            int col = c0 + wc + n * 16 + li;
            float bs = bias[col];
            int row0 = r0 + wr + m * 16 + g * 4;
#pragma unroll
            for (int r = 0; r < 4; ++r)
                C[(size_t)(row0 + r) * D_MODEL + col] = acc[m][n][r] + bs;
        }
    }
}

// ------- Vsum[bh][dh] = sum_{s >= loop_end_b} Vt[bh][dh][s]  (f32), 128-granular -------
// (Vt is block-permuted, but loop_end is 128-aligned and we sum whole blocks ->
//  permutation-invariant.)
__global__ __launch_bounds__(256) void vsum_kernel(const __hip_bfloat16* __restrict__ Vt,
                                                   const int* __restrict__ thresholds,
                                                   float* __restrict__ Vsum) {
    int bh = blockIdx.x, b = bh >> 4;
    int thresh = thresholds[b];
    int loop_end = min(SEQ, ((thresh + 127) >> 7) << 7);
    int t = threadIdx.x;
    int dh = t >> 2, sub = t & 3;
    const __hip_bfloat16* row = Vt + ((size_t)bh * DH + dh) * SEQ;
    float s = 0.f;
    for (int s0 = loop_end + sub * 8; s0 < SEQ; s0 += 32) {
        short8 v = *(const short8*)(row + s0);
#pragma unroll
        for (int j = 0; j < 8; ++j) {
            unsigned short us = (unsigned short)v[j];
            s += __bfloat162float(*(__hip_bfloat16*)&us);
        }
    }
    s += __shfl_xor(s, 1);
    s += __shfl_xor(s, 2);
    if (sub == 0) Vsum[bh * DH + dh] = s;
}

// ----- flash MFMA attention: KVBLK=128, 8 waves, permuted-V PV with b128 reads -----
// PV reads halved: 16 ds_read_b128/wave/tile (each feeds 2 K=16 MFMAs) vs 32 b64.
// Qp/Kp: [B*H][S][DH] bf16 (Q pre-scaled by log2e).  Vt: [B*H][DH][S] bf16, PERMUTED
// within 128-key blocks (p = g*32 + ks*4 + rr).
__global__ __launch_bounds__(512, 4) void attn_mfma_kernel(
    const __hip_bfloat16* __restrict__ Qp,
    const __hip_bfloat16* __restrict__ Kp,
    const __hip_bfloat16* __restrict__ Vt,
    const int* __restrict__ thresholds,
    const float* __restrict__ Vsum,
    __hip_bfloat16* __restrict__ AO) {
    __shared__ char lds[65536];   // sK[2][16KB] | sVT[2][16KB]
    char* sK  = lds;
    char* sVT = lds + 32768;

    const int t = threadIdx.x, lane = t & 63, w = t >> 6;   // w in {0..7}
    const int g = lane >> 4, li = lane & 15;
    const int bh = blockIdx.x, b = bh >> 4, h = bh & 15;
    const int q0 = blockIdx.y * 128;
    const int thresh = thresholds[b];
    const int loop_end = min(SEQ, ((thresh + 127) >> 7) << 7);
    const __hip_bfloat16* Qb = Qp + (size_t)bh * SEQ * DH;
    const __hip_bfloat16* Kb = Kp + (size_t)bh * SEQ * DH;
    const __hip_bfloat16* Vb = Vt + (size_t)bh * DH * SEQ;

    // Q as B-fragment (col=q): lane holds Q[q0+w*16+li][kb*32+g*8 ..+8]
    short8 qf[2];
#pragma unroll
    for (int kb = 0; kb < 2; ++kb)
        qf[kb] = *(const short8*)(Qb + (size_t)(q0 + w * 16 + li) * DH + kb * 32 + g * 8);

    // O^T accumulators: col=q(li), row=dh=16n+4g+rr
    f32x4 Oacc[4] = {};
    float mrun = NEG_INF, lpart = 0.f;   // per-lane partial rowsum

    auto stageK = [&](int bb, int kv) {
#pragma unroll
        for (int i = 0; i < 2; ++i) {
            int o = i * 8192 + t * 16;
            int key = o >> 7, slot = (o & 127) >> 4;
            __builtin_amdgcn_global_load_lds(
                AS1C(Kb + (size_t)(kv + key) * DH + ((slot ^ (key & 7)) << 3)),
                AS3(sK + bb * 16384 + i * 8192 + w * 1024), 16, 0, 0);
        }
    };
    auto stageV = [&](int bb, int kv) {
#pragma unroll
        for (int i = 0; i < 2; ++i) {
            int o = i * 8192 + t * 16;
            int dh = o >> 8, slot = (o & 255) >> 4;
            __builtin_amdgcn_global_load_lds(
                AS1C(Vb + (size_t)dh * SEQ + kv + ((slot ^ (dh & 15)) << 3)),
                AS3(sVT + bb * 16384 + i * 8192 + w * 1024), 16, 0, 0);
        }
    };

    stageK(0, 0); stageV(0, 0);
    asm volatile("s_waitcnt vmcnt(0)" ::: "memory");
    __syncthreads();

    int cur = 0;
    for (int kv0 = 0; kv0 < loop_end; kv0 += 128) {
        int nxt = kv0 + 128;
        if (nxt < loop_end) { stageK(cur ^ 1, nxt); stageV(cur ^ 1, nxt); }

        // ---- QK^T swapped: S^T[key][q] = mfma(A=K, B=Q), exp2 domain, 128 keys ----
        f32x4 S[8] = {};
        __builtin_amdgcn_s_setprio(1);
#pragma unroll
        for (int kb = 0; kb < 2; ++kb) {
            short8 kf[8];
#pragma unroll
            for (int n = 0; n < 8; ++n) {
                int key = 16 * n + li;
                kf[n] = *(const short8*)(sK + cur * 16384 + key * 128 +
                                         (((4 * kb + g) ^ (key & 7)) << 4));
            }
#pragma unroll
            for (int n = 0; n < 8; ++n)
                S[n] = __builtin_amdgcn_mfma_f32_16x16x32_bf16(kf[n], qf[kb], S[n], 0, 0, 0);
        }
        __builtin_amdgcn_s_setprio(0);

        if (kv0 + 128 > thresh) {
            // straddle tile only: key = kv0 + 16n + 4g + rr
            int tr = thresh - kv0 - 4 * g;
#pragma unroll
            for (int n = 0; n < 8; ++n)
#pragma unroll
                for (int rr = 0; rr < 4; ++rr)
                    if (16 * n + rr >= tr) S[n][rr] = MASKB2;
        }

        // per-lane row max (lane owns q=li); row-uniform via 2 shuffles
        float mx = S[0][0];
#pragma unroll
        for (int n = 0; n < 8; ++n)
#pragma unroll
            for (int rr = 0; rr < 4; ++rr) mx = fmaxf(mx, S[n][rr]);
        mx = fmaxf(mx, __shfl_xor(mx, 16));
        mx = fmaxf(mx, __shfl_xor(mx, 32));
        float pmax = mx;

        // defer-max (T13)
        if (__any(pmax > mrun + DEFER_THR)) {
            float mn = fmaxf(mrun, pmax);
            float alpha = fexp2(mrun - mn);
            lpart *= alpha;
#pragma unroll
            for (int n = 0; n < 4; ++n)
#pragma unroll
                for (int rr = 0; rr < 4; ++rr) Oacc[n][rr] *= alpha;
            mrun = mn;
        }

        // exp2 + per-lane partial rowsum (no shuffles) + pack into PV B-fragments
        short4v pb[8];
#pragma unroll
        for (int n = 0; n < 8; ++n) {
#pragma unroll
            for (int rr = 0; rr < 4; ++rr) {
                float p = fexp2(S[n][rr] - mrun);
                S[n][rr] = p;
                lpart += p;
            }
            PB u;
            u.u[0] = pk2(S[n][0], S[n][1]);
            u.u[1] = pk2(S[n][2], S[n][3]);
            pb[n] = u.s4;
        }

        // ---- PV: O^T[dh][q] += mfma16x16x16(A=V^T permuted, B=P^T), b128 reads ----
        // va128 at dh*256 + swz(4g+u)*16 holds keys {16(2u)+4g+0..3, 16(2u+1)+4g+0..3}.
        __builtin_amdgcn_s_setprio(1);
#pragma unroll
        for (int u = 0; u < 4; ++u) {
            int slot = 4 * g + u;
#pragma unroll
            for (int n = 0; n < 4; ++n) {
                int dh = 16 * n + li;
                VU vu;
                vu.s8 = *(const short8*)(sVT + cur * 16384 + dh * 256 +
                                         ((slot ^ (dh & 15)) << 4));
                Oacc[n] = __builtin_amdgcn_mfma_f32_16x16x16bf16_1k(vu.h[0], pb[2 * u],
                                                                    Oacc[n], 0, 0, 0);
                Oacc[n] = __builtin_amdgcn_mfma_f32_16x16x16bf16_1k(vu.h[1], pb[2 * u + 1],
                                                                    Oacc[n], 0, 0, 0);
            }
        }
        __builtin_amdgcn_s_setprio(0);

        asm volatile("s_waitcnt vmcnt(0)" ::: "memory");
        __syncthreads();
        cur ^= 1;
    }

    // combine per-lane partial rowsums once
    float lrun = lpart;
    lrun += __shfl_xor(lrun, 16);
    lrun += __shfl_xor(lrun, 32);

    // ---- analytic masked tail: keys in [loop_end, SEQ) all have score MASKB2 ----
    int nmask = SEQ - loop_end;
    if (nmask > 0) {
        const float* vs = Vsum + bh * DH;
        f32x4 vsf[4];
#pragma unroll
        for (int n = 0; n < 4; ++n) vsf[n] = *(const f32x4*)(vs + 16 * n + 4 * g);
        float pu = fexp2(MASKB2 - mrun);
        lrun += (float)nmask * pu;
#pragma unroll
        for (int n = 0; n < 4; ++n)
#pragma unroll
            for (int rr = 0; rr < 4; ++rr) Oacc[n][rr] += pu * vsf[n][rr];
    }

    // ---- epilogue: normalize, write bf16 (8B stores) ----
    float linv = 1.0f / lrun;
    int q = q0 + w * 16 + li;
#pragma unroll
    for (int n = 0; n < 4; ++n) {
        __hip_bfloat16 o4[4];
#pragma unroll
        for (int rr = 0; rr < 4; ++rr) o4[rr] = __float2bfloat16(Oacc[n][rr] * linv);
        *(short4*)(AO + (size_t)(b * SEQ + q) * D_MODEL + h * DH + 16 * n + 4 * g) =
            *(short4*)o4;
    }
}

extern "C" void kernel_launch(void* const* d_in, const int* in_sizes, int n_in,
                              void* d_out, int out_size, void* d_ws, size_t ws_size,
                              hipStream_t stream) {
    const float* queries    = (const float*)d_in[0];
    const float* keys       = (const float*)d_in[1];
    const float* values     = (const float*)d_in[2];
    const int*   thresholds = (const int*)d_in[3];
    const float* Wq = (const float*)d_in[4];
    const float* bq = (const float*)d_in[5];
    const float* Wk = (const float*)d_in[6];
    const float* bk = (const float*)d_in[7];
    const float* Wv = (const float*)d_in[8];
    const float* bv = (const float*)d_in[9];
    const float* W  = (const float*)d_in[10];
    const float* Wo = (const float*)d_in[11];
    const float* bo = (const float*)d_in[12];
    float* out = (float*)d_out;

    char* wsb = (char*)d_ws;
    float* bq2  = (float*)wsb;                         // 4 KB
    float* Vsum = (float*)(wsb + 4096);                // 8 KB
    __hip_bfloat16* XqB = (__hip_bfloat16*)(wsb + 16384);
    __hip_bfloat16* XkB = XqB + (1 << 22);
    __hip_bfloat16* XvB = XkB + (1 << 22);
    __hip_bfloat16* WqT = XvB + (1 << 22);
    __hip_bfloat16* WkT = WqT + (1 << 20);
    __hip_bfloat16* WvT = WkT + (1 << 20);
    __hip_bfloat16* WoT = WvT + (1 << 20);
    __hip_bfloat16* QpB = WoT + (1 << 20);
    __hip_bfloat16* KpB = QpB + (1 << 22);
    __hip_bfloat16* VtB = KpB + (1 << 22);
    __hip_bfloat16* AOB = XqB;   // alias: XqB dead after Q projection

    prep_all_kernel<<<10272, 256, 0, stream>>>(Wq, bq, W, WqT, bq2,
                                               Wk, Wv, Wo, WkT, WvT, WoT,
                                               queries, keys, values, XqB, XkB, XvB);

    gemm_qkv_kernel<<<dim3(8, 32, 3), 256, 0, stream>>>(XqB, XkB, XvB, WqT, WkT, WvT,
                                                        bq2, bk, bv, QpB, KpB, VtB);
    vsum_kernel<<<32, 256, 0, stream>>>(VtB, thresholds, Vsum);

    attn_mfma_kernel<<<dim3(32, 16), 512, 0, stream>>>(QpB, KpB, VtB, thresholds, Vsum, AOB);

    gemm_out_kernel<<<dim3(8, 32), 256, 0, stream>>>(AOB, WoT, bo, out);
}

// Round 23
// 145.915 us; speedup vs baseline: 1.0367x; 1.0007x over previous
//
#include <hip/hip_runtime.h>
#include <hip/hip_bf16.h>

#define D_MODEL 1024
#define NHEADS  16
#define DH      64
#define SEQ     2048
#define BATCH   2

#define LOG2E 1.4426950408889634f
#define MASKB2 (-1e-6f * LOG2E)   // mask value in exp2 domain
#define DEFER_THR 11.5456f        // 8 * log2e
#define NEG_INF (-__builtin_inff())

typedef __attribute__((ext_vector_type(8))) short short8;
typedef __attribute__((ext_vector_type(4))) short short4v;
typedef __attribute__((ext_vector_type(4))) float f32x4;

#define AS1C(p) ((const __attribute__((address_space(1))) void*)(p))
#define AS3(p)  ((__attribute__((address_space(3))) void*)(p))

union PB { short4v s4; unsigned int u[2]; };
union VU { short8 s8; short4v h[2]; };

static __device__ __forceinline__ float fexp2(float x) {
    return __builtin_amdgcn_exp2f(x);   // v_exp_f32
}

static __device__ __forceinline__ unsigned int pk2(float lo, float hi) {
    __hip_bfloat16 a = __float2bfloat16(lo), b = __float2bfloat16(hi);
    unsigned short au = *(unsigned short*)&a, bu = *(unsigned short*)&b;
    return (unsigned int)au | ((unsigned int)bu << 16);
}

// ---- merged prep: [0,1056) fold Wq*W -> WqT bf16 (+bq2); [1056,4128) transpose Wk/Wv/Wo;
//      [4128,10272) convert queries/keys/values fp32 -> bf16 ----
__global__ __launch_bounds__(256) void prep_all_kernel(
    const float* __restrict__ Wq, const float* __restrict__ bq, const float* __restrict__ W,
    __hip_bfloat16* __restrict__ WqT, float* __restrict__ bq2,
    const float* __restrict__ Wk, const float* __restrict__ Wv, const float* __restrict__ Wo,
    __hip_bfloat16* __restrict__ WkT, __hip_bfloat16* __restrict__ WvT,
    __hip_bfloat16* __restrict__ WoT,
    const float* __restrict__ q, const float* __restrict__ k, const float* __restrict__ v,
    __hip_bfloat16* __restrict__ oq, __hip_bfloat16* __restrict__ ok,
    __hip_bfloat16* __restrict__ ov) {
    const int blk = blockIdx.x;
    const int t = threadIdx.x;

    if (blk < 1056) {
        const int c0 = (blk & 31) * 32;
        const int yy = blk >> 5;             // 0..32
        const int h = c0 >> 6, j0 = c0 & 63;
        if (yy == 32) {
            if (t < 32) {
                int col = c0 + t, j = col & 63;
                float s = 0.f;
#pragma unroll
                for (int d = 0; d < DH; ++d) s += bq[h * DH + d] * W[d * DH + j];
                bq2[col] = s * LOG2E;
            }
            return;
        }
        const int r0 = yy * 32;
        __shared__ float sWq[32][68];
        __shared__ float sW[64][36];
        __shared__ float sOut[32][33];
        {
            int lr = t >> 3, lc8 = (t & 7) * 8;
            const float* src = Wq + (size_t)(r0 + lr) * D_MODEL + h * DH + lc8;
            *(float4*)&sWq[lr][lc8]     = *(const float4*)(src);
            *(float4*)&sWq[lr][lc8 + 4] = *(const float4*)(src + 4);
            int d = t >> 2, c8 = (t & 3) * 8;
            const float* wsrc = W + (size_t)d * DH + j0 + c8;
            *(float4*)&sW[d][c8]     = *(const float4*)(wsrc);
            *(float4*)&sW[d][c8 + 4] = *(const float4*)(wsrc + 4);
        }
        __syncthreads();
        {
            int col_loc = t & 31, rq = t >> 5;
            float acc0 = 0.f, acc1 = 0.f, acc2 = 0.f, acc3 = 0.f;
#pragma unroll
            for (int d = 0; d < 64; ++d) {
                float wv = sW[d][col_loc];
                acc0 += sWq[rq * 4 + 0][d] * wv;
                acc1 += sWq[rq * 4 + 1][d] * wv;
                acc2 += sWq[rq * 4 + 2][d] * wv;
                acc3 += sWq[rq * 4 + 3][d] * wv;
            }
            sOut[col_loc][rq * 4 + 0] = acc0 * LOG2E;
            sOut[col_loc][rq * 4 + 1] = acc1 * LOG2E;
            sOut[col_loc][rq * 4 + 2] = acc2 * LOG2E;
            sOut[col_loc][rq * 4 + 3] = acc3 * LOG2E;
        }
        __syncthreads();
        {
            int orow = t >> 3, oc4 = (t & 7) * 4;
            __hip_bfloat16 o4[4];
#pragma unroll
            for (int i = 0; i < 4; ++i) o4[i] = __float2bfloat16(sOut[orow][oc4 + i]);
            *(short4*)(WqT + (size_t)(c0 + orow) * D_MODEL + r0 + oc4) = *(short4*)o4;
        }
    } else if (blk < 4128) {
        __shared__ float sT[32][33];
        int r = blk - 1056;
        int z = r >> 10; r &= 1023;
        const float* Win = (z == 0) ? Wk : (z == 1) ? Wv : Wo;
        __hip_bfloat16* Wt = (z == 0) ? WkT : (z == 1) ? WvT : WoT;
        int n0 = (r & 31) * 32, k0 = (r >> 5) * 32;
        int tx = t & 31, ty = t >> 5;
#pragma unroll
        for (int i = 0; i < 4; ++i)
            sT[ty + i * 8][tx] = Win[(size_t)(k0 + ty + i * 8) * D_MODEL + n0 + tx];
        __syncthreads();
#pragma unroll
        for (int i = 0; i < 4; ++i)
            Wt[(size_t)(n0 + ty + i * 8) * D_MODEL + k0 + tx] =
                __float2bfloat16(sT[tx][ty + i * 8]);
    } else {
        int idx = blk - 4128;                    // 0..6143
        int z = idx >> 11;
        int i = (idx & 2047) * 256 + t;
        const float* in = (z == 0) ? q : (z == 1) ? k : v;
        __hip_bfloat16* out = (z == 0) ? oq : (z == 1) ? ok : ov;
        float4 a = *(const float4*)(in + (size_t)i * 8);
        float4 b = *(const float4*)(in + (size_t)i * 8 + 4);
        __hip_bfloat16 o[8];
        o[0] = __float2bfloat16(a.x); o[1] = __float2bfloat16(a.y);
        o[2] = __float2bfloat16(a.z); o[3] = __float2bfloat16(a.w);
        o[4] = __float2bfloat16(b.x); o[5] = __float2bfloat16(b.y);
        o[6] = __float2bfloat16(b.z); o[7] = __float2bfloat16(b.w);
        *(short8*)(out + (size_t)i * 8) = *(short8*)o;
    }
}

// ============ GEMM core (128x128, BK=32, 2-phase dbuf) + T1 bijective XCD swizzle ==========
#define GEMM_CORE(A_, BT_)                                                                  \
    __shared__ __hip_bfloat16 sA[2][128 * 32];                                              \
    __shared__ __hip_bfloat16 sB[2][128 * 32];                                              \
    const int t = threadIdx.x;                                                              \
    const int lane = t & 63, w = t >> 6;                                                    \
    const int g = lane >> 4, li = lane & 15;                                                \
    const int lin = blockIdx.y * 8 + blockIdx.x;                                            \
    const int ob = (lin & 7) * 32 + (lin >> 3);                                             \
    const int r0 = (ob >> 3) * 128, c0 = (ob & 7) * 128;                                    \
    const int wr = (w >> 1) * 64, wc = (w & 1) * 64;                                        \
    f32x4 acc[4][4] = {};                                                                   \
    auto stage = [&](int bb, int k0) {                                                      \
        _Pragma("unroll")                                                                   \
        for (int i = 0; i < 2; ++i) {                                                       \
            int o = (i * 4 + w) * 1024 + lane * 16;                                         \
            int row = o >> 6, ce = (o & 63) >> 1;                                           \
            __builtin_amdgcn_global_load_lds(AS1C(A_ + (size_t)(r0 + row) * 1024 + k0 + ce),\
                                             AS3((char*)sA[bb] + (i * 4 + w) * 1024), 16, 0, 0); \
            __builtin_amdgcn_global_load_lds(AS1C(BT_ + (size_t)(c0 + row) * 1024 + k0 + ce),\
                                             AS3((char*)sB[bb] + (i * 4 + w) * 1024), 16, 0, 0); \
        }                                                                                   \
    };                                                                                      \
    stage(0, 0);                                                                            \
    asm volatile("s_waitcnt vmcnt(0)" ::: "memory");                                        \
    __syncthreads();                                                                        \
    int cur = 0;                                                                            \
    for (int k0 = 0; k0 < 1024; k0 += 32) {                                                 \
        if (k0 + 32 < 1024) stage(cur ^ 1, k0 + 32);                                        \
        short8 af[4], bf[4];                                                                \
        _Pragma("unroll")                                                                   \
        for (int m = 0; m < 4; ++m)                                                         \
            af[m] = *(const short8*)(sA[cur] + (wr + m * 16 + li) * 32 + g * 8);            \
        _Pragma("unroll")                                                                   \
        for (int n = 0; n < 4; ++n)                                                         \
            bf[n] = *(const short8*)(sB[cur] + (wc + n * 16 + li) * 32 + g * 8);            \
        _Pragma("unroll")                                                                   \
        for (int m = 0; m < 4; ++m)                                                         \
            _Pragma("unroll")                                                               \
            for (int n = 0; n < 4; ++n)                                                     \
                acc[m][n] = __builtin_amdgcn_mfma_f32_16x16x32_bf16(af[m], bf[n], acc[m][n], 0, 0, 0); \
        asm volatile("s_waitcnt vmcnt(0)" ::: "memory");                                    \
        __syncthreads();                                                                    \
        cur ^= 1;                                                                           \
    }

// ---------------- QKV projections, one launch (grid.z selects which) ----------------
// z=2 (V) writes Vt in the PV-PERMUTED layout: within each 128-key block,
// key s (= 16ks+4g2+rr) is stored at p = g2*32 + ks*4 + rr.
__global__ __launch_bounds__(256) void gemm_qkv_kernel(
    const __hip_bfloat16* __restrict__ Xq, const __hip_bfloat16* __restrict__ Xk,
    const __hip_bfloat16* __restrict__ Xv,
    const __hip_bfloat16* __restrict__ WqT, const __hip_bfloat16* __restrict__ WkT,
    const __hip_bfloat16* __restrict__ WvT,
    const float* __restrict__ bq2, const float* __restrict__ bk, const float* __restrict__ bv,
    __hip_bfloat16* __restrict__ Qp, __hip_bfloat16* __restrict__ Kp,
    __hip_bfloat16* __restrict__ Vt) {
    const int z = blockIdx.z;
    const __hip_bfloat16* A  = (z == 0) ? Xq  : (z == 1) ? Xk  : Xv;
    const __hip_bfloat16* BT = (z == 0) ? WqT : (z == 1) ? WkT : WvT;
    const float* bias        = (z == 0) ? bq2 : (z == 1) ? bk  : bv;
    __hip_bfloat16* C        = (z == 0) ? Qp  : (z == 1) ? Kp  : Vt;

    GEMM_CORE(A, BT)

#pragma unroll
    for (int m = 0; m < 4; ++m) {
#pragma unroll
        for (int n = 0; n < 4; ++n) {
            int col = c0 + wc + n * 16 + li;
            float bs = bias[col];
            int row0 = r0 + wr + m * 16 + g * 4;
            int h = col >> 6, d = col & 63;
            if (z == 2) {
                int b = row0 >> 11, s0 = row0 & 2047;
                int sp = (s0 & ~127) | (((s0 >> 2) & 3) << 5) | (((s0 >> 4) & 7) << 2);
                __hip_bfloat16 o4[4];
#pragma unroll
                for (int r = 0; r < 4; ++r) o4[r] = __float2bfloat16(acc[m][n][r] + bs);
                *(short4*)(C + (((size_t)(b * NHEADS + h)) * DH + d) * SEQ + sp) = *(short4*)o4;
            } else {
#pragma unroll
                for (int r = 0; r < 4; ++r) {
                    int row = row0 + r;
                    int b = row >> 11, s = row & 2047;
                    C[(((size_t)(b * NHEADS + h)) * SEQ + s) * DH + d] =
                        __float2bfloat16(acc[m][n][r] + bs);
                }
            }
        }
    }
}

// ---------------- output projection (fp32 out) ----------------
__global__ __launch_bounds__(256) void gemm_out_kernel(
    const __hip_bfloat16* __restrict__ A, const __hip_bfloat16* __restrict__ BT,
    const float* __restrict__ bias, float* __restrict__ C) {
    GEMM_CORE(A, BT)
#pragma unroll
    for (int m = 0; m < 4; ++m) {
#pragma unroll
        for (int n = 0; n < 4; ++n) {
            int col = c0 + wc + n * 16 + li;
            float bs = bias[col];
            int row0 = r0 + wr + m * 16 + g * 4;
#pragma unroll
            for (int r = 0; r < 4; ++r)
                C[(size_t)(row0 + r) * D_MODEL + col] = acc[m][n][r] + bs;
        }
    }
}

// ------- Vsum[bh][dh] = sum_{s >= loop_end_b} Vt[bh][dh][s]  (f32), 128-granular -------
__global__ __launch_bounds__(256) void vsum_kernel(const __hip_bfloat16* __restrict__ Vt,
                                                   const int* __restrict__ thresholds,
                                                   float* __restrict__ Vsum) {
    int bh = blockIdx.x, b = bh >> 4;
    int thresh = thresholds[b];
    int loop_end = min(SEQ, ((thresh + 127) >> 7) << 7);
    int t = threadIdx.x;
    int dh = t >> 2, sub = t & 3;
    const __hip_bfloat16* row = Vt + ((size_t)bh * DH + dh) * SEQ;
    float s = 0.f;
    for (int s0 = loop_end + sub * 8; s0 < SEQ; s0 += 32) {
        short8 v = *(const short8*)(row + s0);
#pragma unroll
        for (int j = 0; j < 8; ++j) {
            unsigned short us = (unsigned short)v[j];
            s += __bfloat162float(*(__hip_bfloat16*)&us);
        }
    }
    s += __shfl_xor(s, 1);
    s += __shfl_xor(s, 2);
    if (sub == 0) Vsum[bh * DH + dh] = s;
}

// ----- flash MFMA attention: KVBLK=128, 8 waves, permuted-V, SINGLE-buffered V -----
// LDS 48KB (sK dbuf 32K + sVT 16K) -> 3 blocks/CU (24 waves/CU, +50% latency hiding).
// Schedule/tile: stageK(t+1) -> QK -> softmax -> vmcnt(2)[drain V(t), keep K(t+1)]
//   -> B1 -> PV -> vmcnt(0)[drain K(t+1), issued a full tile ago] -> B2 -> stageV(t+1).
// V(t+1) prefetch latency is covered by QK(t+1)+softmax(t+1).
__global__ __launch_bounds__(512) void attn_mfma_kernel(
    const __hip_bfloat16* __restrict__ Qp,
    const __hip_bfloat16* __restrict__ Kp,
    const __hip_bfloat16* __restrict__ Vt,
    const int* __restrict__ thresholds,
    const float* __restrict__ Vsum,
    __hip_bfloat16* __restrict__ AO) {
    __shared__ char lds[49152];   // sK[2][16KB] | sVT[16KB]
    char* sK  = lds;
    char* sVT = lds + 32768;

    const int t = threadIdx.x, lane = t & 63, w = t >> 6;   // w in {0..7}
    const int g = lane >> 4, li = lane & 15;
    const int bh = blockIdx.x, b = bh >> 4, h = bh & 15;
    const int q0 = blockIdx.y * 128;
    const int thresh = thresholds[b];
    const int loop_end = min(SEQ, ((thresh + 127) >> 7) << 7);
    const __hip_bfloat16* Qb = Qp + (size_t)bh * SEQ * DH;
    const __hip_bfloat16* Kb = Kp + (size_t)bh * SEQ * DH;
    const __hip_bfloat16* Vb = Vt + (size_t)bh * DH * SEQ;

    // Q as B-fragment (col=q): lane holds Q[q0+w*16+li][kb*32+g*8 ..+8]
    short8 qf[2];
#pragma unroll
    for (int kb = 0; kb < 2; ++kb)
        qf[kb] = *(const short8*)(Qb + (size_t)(q0 + w * 16 + li) * DH + kb * 32 + g * 8);

    // O^T accumulators: col=q(li), row=dh=16n+4g+rr
    f32x4 Oacc[4] = {};
    float mrun = NEG_INF, lpart = 0.f;   // per-lane partial rowsum

    auto stageK = [&](int bb, int kv) {
#pragma unroll
        for (int i = 0; i < 2; ++i) {
            int o = i * 8192 + t * 16;
            int key = o >> 7, slot = (o & 127) >> 4;
            __builtin_amdgcn_global_load_lds(
                AS1C(Kb + (size_t)(kv + key) * DH + ((slot ^ (key & 7)) << 3)),
                AS3(sK + bb * 16384 + i * 8192 + w * 1024), 16, 0, 0);
        }
    };
    auto stageV = [&](int kv) {
#pragma unroll
        for (int i = 0; i < 2; ++i) {
            int o = i * 8192 + t * 16;
            int dh = o >> 8, slot = (o & 255) >> 4;
            __builtin_amdgcn_global_load_lds(
                AS1C(Vb + (size_t)dh * SEQ + kv + ((slot ^ (dh & 15)) << 3)),
                AS3(sVT + i * 8192 + w * 1024), 16, 0, 0);
        }
    };

    stageK(0, 0); stageV(0);
    asm volatile("s_waitcnt vmcnt(0)" ::: "memory");
    __syncthreads();

    int cur = 0;
    for (int kv0 = 0; kv0 < loop_end; kv0 += 128) {
        int nxt = kv0 + 128;
        bool more = (nxt < loop_end);
        if (more) stageK(cur ^ 1, nxt);

        // ---- QK^T swapped: S^T[key][q] = mfma(A=K, B=Q), exp2 domain, 128 keys ----
        f32x4 S[8] = {};
        __builtin_amdgcn_s_setprio(1);
#pragma unroll
        for (int kb = 0; kb < 2; ++kb) {
            short8 kf[8];
#pragma unroll
            for (int n = 0; n < 8; ++n) {
                int key = 16 * n + li;
                kf[n] = *(const short8*)(sK + cur * 16384 + key * 128 +
                                         (((4 * kb + g) ^ (key & 7)) << 4));
            }
#pragma unroll
            for (int n = 0; n < 8; ++n)
                S[n] = __builtin_amdgcn_mfma_f32_16x16x32_bf16(kf[n], qf[kb], S[n], 0, 0, 0);
        }
        __builtin_amdgcn_s_setprio(0);

        if (kv0 + 128 > thresh) {
            // straddle tile only: key = kv0 + 16n + 4g + rr
            int tr = thresh - kv0 - 4 * g;
#pragma unroll
            for (int n = 0; n < 8; ++n)
#pragma unroll
                for (int rr = 0; rr < 4; ++rr)
                    if (16 * n + rr >= tr) S[n][rr] = MASKB2;
        }

        // per-lane row max (lane owns q=li); row-uniform via 2 shuffles
        float mx = S[0][0];
#pragma unroll
        for (int n = 0; n < 8; ++n)
#pragma unroll
            for (int rr = 0; rr < 4; ++rr) mx = fmaxf(mx, S[n][rr]);
        mx = fmaxf(mx, __shfl_xor(mx, 16));
        mx = fmaxf(mx, __shfl_xor(mx, 32));
        float pmax = mx;

        // defer-max (T13)
        if (__any(pmax > mrun + DEFER_THR)) {
            float mn = fmaxf(mrun, pmax);
            float alpha = fexp2(mrun - mn);
            lpart *= alpha;
#pragma unroll
            for (int n = 0; n < 4; ++n)
#pragma unroll
                for (int rr = 0; rr < 4; ++rr) Oacc[n][rr] *= alpha;
            mrun = mn;
        }

        // exp2 + per-lane partial rowsum (no shuffles) + pack into PV B-fragments
        short4v pb[8];
#pragma unroll
        for (int n = 0; n < 8; ++n) {
#pragma unroll
            for (int rr = 0; rr < 4; ++rr) {
                float p = fexp2(S[n][rr] - mrun);
                S[n][rr] = p;
                lpart += p;
            }
            PB u;
            u.u[0] = pk2(S[n][0], S[n][1]);
            u.u[1] = pk2(S[n][2], S[n][3]);
            pb[n] = u.s4;
        }

        // drain V(t) (its 2 loads are oldest); keep K(t+1) in flight when staged
        if (more) asm volatile("s_waitcnt vmcnt(2)" ::: "memory");
        else      asm volatile("s_waitcnt vmcnt(0)" ::: "memory");
        __syncthreads();   // B1: all waves' V(t) visible

        // ---- PV: O^T[dh][q] += mfma16x16x16(A=V^T permuted, B=P^T), b128 reads ----
        __builtin_amdgcn_s_setprio(1);
#pragma unroll
        for (int u = 0; u < 4; ++u) {
            int slot = 4 * g + u;
#pragma unroll
            for (int n = 0; n < 4; ++n) {
                int dh = 16 * n + li;
                VU vu;
                vu.s8 = *(const short8*)(sVT + dh * 256 + ((slot ^ (dh & 15)) << 4));
                Oacc[n] = __builtin_amdgcn_mfma_f32_16x16x16bf16_1k(vu.h[0], pb[2 * u],
                                                                    Oacc[n], 0, 0, 0);
                Oacc[n] = __builtin_amdgcn_mfma_f32_16x16x16bf16_1k(vu.h[1], pb[2 * u + 1],
                                                                    Oacc[n], 0, 0, 0);
            }
        }
        __builtin_amdgcn_s_setprio(0);

        // drain K(t+1) (issued a full tile ago) before next tile's QK reads it
        asm volatile("s_waitcnt vmcnt(0)" ::: "memory");
        __syncthreads();   // B2: PV reads done -> safe to overwrite sVT
        if (more) stageV(nxt);
        cur ^= 1;
    }

    // combine per-lane partial rowsums once
    float lrun = lpart;
    lrun += __shfl_xor(lrun, 16);
    lrun += __shfl_xor(lrun, 32);

    // ---- analytic masked tail: keys in [loop_end, SEQ) all have score MASKB2 ----
    int nmask = SEQ - loop_end;
    if (nmask > 0) {
        const float* vs = Vsum + bh * DH;
        f32x4 vsf[4];
#pragma unroll
        for (int n = 0; n < 4; ++n) vsf[n] = *(const f32x4*)(vs + 16 * n + 4 * g);
        float pu = fexp2(MASKB2 - mrun);
        lrun += (float)nmask * pu;
#pragma unroll
        for (int n = 0; n < 4; ++n)
#pragma unroll
            for (int rr = 0; rr < 4; ++rr) Oacc[n][rr] += pu * vsf[n][rr];
    }

    // ---- epilogue: normalize, write bf16 (8B stores) ----
    float linv = 1.0f / lrun;
    int q = q0 + w * 16 + li;
#pragma unroll
    for (int n = 0; n < 4; ++n) {
        __hip_bfloat16 o4[4];
#pragma unroll
        for (int rr = 0; rr < 4; ++rr) o4[rr] = __float2bfloat16(Oacc[n][rr] * linv);
        *(short4*)(AO + (size_t)(b * SEQ + q) * D_MODEL + h * DH + 16 * n + 4 * g) =
            *(short4*)o4;
    }
}

extern "C" void kernel_launch(void* const* d_in, const int* in_sizes, int n_in,
                              void* d_out, int out_size, void* d_ws, size_t ws_size,
                              hipStream_t stream) {
    const float* queries    = (const float*)d_in[0];
    const float* keys       = (const float*)d_in[1];
    const float* values     = (const float*)d_in[2];
    const int*   thresholds = (const int*)d_in[3];
    const float* Wq = (const float*)d_in[4];
    const float* bq = (const float*)d_in[5];
    const float* Wk = (const float*)d_in[6];
    const float* bk = (const float*)d_in[7];
    const float* Wv = (const float*)d_in[8];
    const float* bv = (const float*)d_in[9];
    const float* W  = (const float*)d_in[10];
    const float* Wo = (const float*)d_in[11];
    const float* bo = (const float*)d_in[12];
    float* out = (float*)d_out;

    char* wsb = (char*)d_ws;
    float* bq2  = (float*)wsb;                         // 4 KB
    float* Vsum = (float*)(wsb + 4096);                // 8 KB
    __hip_bfloat16* XqB = (__hip_bfloat16*)(wsb + 16384);
    __hip_bfloat16* XkB = XqB + (1 << 22);
    __hip_bfloat16* XvB = XkB + (1 << 22);
    __hip_bfloat16* WqT = XvB + (1 << 22);
    __hip_bfloat16* WkT = WqT + (1 << 20);
    __hip_bfloat16* WvT = WkT + (1 << 20);
    __hip_bfloat16* WoT = WvT + (1 << 20);
    __hip_bfloat16* QpB = WoT + (1 << 20);
    __hip_bfloat16* KpB = QpB + (1 << 22);
    __hip_bfloat16* VtB = KpB + (1 << 22);
    __hip_bfloat16* AOB = XqB;   // alias: XqB dead after Q projection

    prep_all_kernel<<<10272, 256, 0, stream>>>(Wq, bq, W, WqT, bq2,
                                               Wk, Wv, Wo, WkT, WvT, WoT,
                                               queries, keys, values, XqB, XkB, XvB);

    gemm_qkv_kernel<<<dim3(8, 32, 3), 256, 0, stream>>>(XqB, XkB, XvB, WqT, WkT, WvT,
                                                        bq2, bk, bv, QpB, KpB, VtB);
    vsum_kernel<<<32, 256, 0, stream>>>(VtB, thresholds, Vsum);

    attn_mfma_kernel<<<dim3(32, 16), 512, 0, stream>>>(QpB, KpB, VtB, thresholds, Vsum, AOB);

    gemm_out_kernel<<<dim3(8, 32), 256, 0, stream>>>(AOB, WoT, bo, out);
}